// Round 1
// baseline (1447.120 us; speedup 1.0000x reference)
//
#include <hip/hip_runtime.h>

#define LRELU(v) ((v) > 0.f ? (v) : 0.2f * (v))

__device__ __forceinline__ void atomicMaxF(float* addr, float v) {
    // works for mixed signs when buffer initialized to -inf
    if (v >= 0.f) atomicMax((int*)addr, __float_as_int(v));
    else          atomicMin((unsigned int*)addr, __float_as_uint(v));
}

__global__ void fill_neginf_k(float* __restrict__ p, int n) {
    int i = blockIdx.x * blockDim.x + threadIdx.x;
    if (i < n) p[i] = -__builtin_inff();
}

// C[M,256] = A[M,128] @ B[128,256]; 256 thr/block, 8 rows/block, 1 col/thread
__global__ void gemm_k128_n256(const float* __restrict__ A, const float* __restrict__ B,
                               float* __restrict__ C, int M) {
    __shared__ float As[8][128];
    const int row0 = blockIdx.x * 8;
    if (row0 >= M) return;
    const int tid = threadIdx.x;
    ((float4*)&As[0][0])[tid] = ((const float4*)(A + (size_t)row0 * 128))[tid];
    __syncthreads();
    float acc[8] = {0.f, 0.f, 0.f, 0.f, 0.f, 0.f, 0.f, 0.f};
    const float* __restrict__ Bc = B + tid;
#pragma unroll 4
    for (int k = 0; k < 128; ++k) {
        float wv = Bc[(size_t)k * 256];
#pragma unroll
        for (int r = 0; r < 8; ++r) acc[r] += As[r][k] * wv;
    }
#pragma unroll
    for (int r = 0; r < 8; ++r) C[(size_t)(row0 + r) * 256 + tid] = acc[r];
}

// C[M,64] = A[M,256] @ B[256,64]; 256 thr = 4 groups x 64 cols, 16 rows/block
__global__ void gemm_k256_n64(const float* __restrict__ A, const float* __restrict__ B,
                              float* __restrict__ C, int M) {
    __shared__ float As[16][256];
    const int row0 = blockIdx.x * 16;
    if (row0 >= M) return;
    const int tid = threadIdx.x;
    {
        const float4* src = (const float4*)(A + (size_t)row0 * 256);
        float4* dstl = (float4*)&As[0][0];
#pragma unroll
        for (int i = 0; i < 4; ++i) dstl[tid + i * 256] = src[tid + i * 256];
    }
    __syncthreads();
    const int col = tid & 63, g = tid >> 6;
    float acc[4] = {0.f, 0.f, 0.f, 0.f};
    const float* __restrict__ Bc = B + col;
#pragma unroll 4
    for (int k = 0; k < 256; ++k) {
        float wv = Bc[(size_t)k * 64];
#pragma unroll
        for (int r = 0; r < 4; ++r) acc[r] += As[g * 4 + r][k] * wv;
    }
#pragma unroll
    for (int r = 0; r < 4; ++r) C[(size_t)(row0 + g * 4 + r) * 64 + col] = acc[r];
}

// a_s[n,h] = dot(h1[n,h,:], att_src[h,:]); H=4, C=64; one block per node
__global__ void attn_h4(const float* __restrict__ h, const float* __restrict__ asrc,
                        const float* __restrict__ adst, float* __restrict__ os,
                        float* __restrict__ od, int N) {
    const int n = blockIdx.x;
    if (n >= N) return;
    const int t = threadIdx.x;            // 256
    float v = h[(size_t)n * 256 + t];
    float s = v * asrc[t];
    float d = v * adst[t];
#pragma unroll
    for (int m = 1; m < 64; m <<= 1) { s += __shfl_xor(s, m); d += __shfl_xor(d, m); }
    if ((t & 63) == 0) { os[n * 4 + (t >> 6)] = s; od[n * 4 + (t >> 6)] = d; }
}

// H=1, C=64; 4 nodes per 256-thread block
__global__ void attn_h1(const float* __restrict__ h, const float* __restrict__ asrc,
                        const float* __restrict__ adst, float* __restrict__ os,
                        float* __restrict__ od, int N) {
    const int n = blockIdx.x * 4 + (threadIdx.x >> 6);
    if (n >= N) return;
    const int c = threadIdx.x & 63;
    float v = h[(size_t)n * 64 + c];
    float s = v * asrc[c];
    float d = v * adst[c];
#pragma unroll
    for (int m = 1; m < 64; m <<= 1) { s += __shfl_xor(s, m); d += __shfl_xor(d, m); }
    if (c == 0) { os[n] = s; od[n] = d; }
}

template <int H>
__global__ void edge_max_k(const int* __restrict__ ei, int E, int N,
                           const float* __restrict__ as, const float* __restrict__ ad,
                           float* __restrict__ mx) {
    int e = blockIdx.x * blockDim.x + threadIdx.x;
    if (e >= E + N) return;
    int s, d;
    if (e < E) { s = ei[e]; d = ei[E + e]; } else { s = d = e - E; }
#pragma unroll
    for (int h = 0; h < H; ++h) {
        float v = as[s * H + h] + ad[d * H + h];
        atomicMaxF(&mx[d * H + h], LRELU(v));
    }
}

template <int H>
__global__ void edge_sum_k(const int* __restrict__ ei, int E, int N,
                           const float* __restrict__ as, const float* __restrict__ ad,
                           const float* __restrict__ mx, float* __restrict__ den) {
    int e = blockIdx.x * blockDim.x + threadIdx.x;
    if (e >= E + N) return;
    int s, d;
    if (e < E) { s = ei[e]; d = ei[E + e]; } else { s = d = e - E; }
#pragma unroll
    for (int h = 0; h < H; ++h) {
        float v = LRELU(as[s * H + h] + ad[d * H + h]);
        atomicAdd(&den[d * H + h], __expf(v - mx[d * H + h]));
    }
}

// one 64-lane wave per edge; lane = channel; C=64
template <int H>
__global__ void edge_scatter_k(const int* __restrict__ ei, int E, int N,
                               const float* __restrict__ as, const float* __restrict__ ad,
                               const float* __restrict__ mx, const float* __restrict__ den,
                               const float* __restrict__ hsrc, float* __restrict__ agg) {
    int w = (blockIdx.x * blockDim.x + threadIdx.x) >> 6;
    if (w >= E + N) return;
    const int lane = threadIdx.x & 63;
    int s, d;
    if (w < E) { s = ei[w]; d = ei[E + w]; } else { s = d = w - E; }
#pragma unroll
    for (int h = 0; h < H; ++h) {
        float v = LRELU(as[s * H + h] + ad[d * H + h]);
        float alpha = __expf(v - mx[d * H + h]) / den[d * H + h];
        atomicAdd(&agg[((size_t)d * H + h) * 64 + lane],
                  alpha * hsrc[((size_t)s * H + h) * 64 + lane]);
    }
}

__global__ void bias_relu_k(float* __restrict__ a, const float* __restrict__ b, int total) {
    int i = blockIdx.x * blockDim.x + threadIdx.x;
    if (i < total) {
        float v = a[i] + b[i & 255];
        a[i] = v > 0.f ? v : 0.f;
    }
}

// out[n,c] = (agg[n,c]+b[c]) / max(||row||, 1e-12); 4 nodes/block
__global__ void bias_norm_k(const float* __restrict__ agg, const float* __restrict__ b,
                            float* __restrict__ out, int N) {
    const int n = blockIdx.x * 4 + (threadIdx.x >> 6);
    if (n >= N) return;
    const int c = threadIdx.x & 63;
    float v = agg[(size_t)n * 64 + c] + b[c];
    float ss = v * v;
#pragma unroll
    for (int m = 1; m < 64; m <<= 1) ss += __shfl_xor(ss, m);
    float nrm = fmaxf(sqrtf(ss), 1e-12f);
    out[(size_t)n * 64 + c] = v / nrm;
}

extern "C" void kernel_launch(void* const* d_in, const int* in_sizes, int n_in,
                              void* d_out, int out_size, void* d_ws, size_t ws_size,
                              hipStream_t stream) {
    const float* x   = (const float*)d_in[0];
    const int*   ei1 = (const int*)d_in[1];
    const int*   ei2 = (const int*)d_in[2];
    const float* W1  = (const float*)d_in[3];
    const float* as1 = (const float*)d_in[4];
    const float* ad1 = (const float*)d_in[5];
    const float* b1  = (const float*)d_in[6];
    const float* W2  = (const float*)d_in[7];
    const float* as2 = (const float*)d_in[8];
    const float* ad2 = (const float*)d_in[9];
    const float* b2  = (const float*)d_in[10];
    float* out = (float*)d_out;

    const int N  = in_sizes[0] / 128;
    const int E1 = in_sizes[1] / 2;
    const int E2 = in_sizes[2] / 2;

    // workspace layout (floats)
    float* base = (float*)d_ws;
    float* h1   = base;                         // N*256
    float* agg1 = h1 + (size_t)N * 256;         // N*256
    float* m1   = agg1 + (size_t)N * 256;       // N*4
    float* m2   = m1 + (size_t)N * 4;           // N      (m1..m2 contiguous: 5N)
    float* den1 = m2 + N;                       // N*4
    float* den2 = den1 + (size_t)N * 4;         // N      (den1..den2 contiguous: 5N)
    float* s1   = den2 + N;                     // N*4
    float* d1v  = s1 + (size_t)N * 4;           // N*4
    float* s2   = d1v + (size_t)N * 4;          // N
    float* d2v  = s2 + N;                       // N
    float* h2   = h1;                           // N*64 (reuse after layer 1)
    float* agg2 = h1 + (size_t)N * 64;          // N*64 (reuse)

    const int EN1 = E1 + N, EN2 = E2 + N;

    // init
    hipMemsetAsync(agg1, 0, (size_t)N * 256 * sizeof(float), stream);
    hipMemsetAsync(den1, 0, (size_t)N * 5 * sizeof(float), stream);
    fill_neginf_k<<<(N * 5 + 255) / 256, 256, 0, stream>>>(m1, N * 5);

    // ---- layer 1 ----
    gemm_k128_n256<<<(N + 7) / 8, 256, 0, stream>>>(x, W1, h1, N);
    attn_h4<<<N, 256, 0, stream>>>(h1, as1, ad1, s1, d1v, N);
    edge_max_k<4><<<(EN1 + 255) / 256, 256, 0, stream>>>(ei1, E1, N, s1, d1v, m1);
    edge_sum_k<4><<<(EN1 + 255) / 256, 256, 0, stream>>>(ei1, E1, N, s1, d1v, m1, den1);
    edge_scatter_k<4><<<(EN1 + 3) / 4, 256, 0, stream>>>(ei1, E1, N, s1, d1v, m1, den1, h1, agg1);
    bias_relu_k<<<((int)((size_t)N * 256) + 255) / 256, 256, 0, stream>>>(agg1, b1, N * 256);

    // ---- layer 2 ----
    gemm_k256_n64<<<(N + 15) / 16, 256, 0, stream>>>(agg1, W2, h2, N);
    attn_h1<<<(N + 3) / 4, 256, 0, stream>>>(h2, as2, ad2, s2, d2v, N);
    hipMemsetAsync(agg2, 0, (size_t)N * 64 * sizeof(float), stream);
    edge_max_k<1><<<(EN2 + 255) / 256, 256, 0, stream>>>(ei2, E2, N, s2, d2v, m2);
    edge_sum_k<1><<<(EN2 + 255) / 256, 256, 0, stream>>>(ei2, E2, N, s2, d2v, m2, den2);
    edge_scatter_k<1><<<(EN2 + 3) / 4, 256, 0, stream>>>(ei2, E2, N, s2, d2v, m2, den2, h2, agg2);

    // ---- final: bias + L2 normalize ----
    bias_norm_k<<<(N + 3) / 4, 256, 0, stream>>>(agg2, b2, out, N);
}

// Round 2
// 609.762 us; speedup vs baseline: 2.3733x; 2.3733x over previous
//
#include <hip/hip_runtime.h>

#define LRELU(v) ((v) > 0.f ? (v) : 0.2f * (v))

// ---------------- GEMMs (unchanged from round 1) ----------------

// C[M,256] = A[M,128] @ B[128,256]; 256 thr/block, 8 rows/block, 1 col/thread
__global__ void gemm_k128_n256(const float* __restrict__ A, const float* __restrict__ B,
                               float* __restrict__ C, int M) {
    __shared__ float As[8][128];
    const int row0 = blockIdx.x * 8;
    if (row0 >= M) return;
    const int tid = threadIdx.x;
    ((float4*)&As[0][0])[tid] = ((const float4*)(A + (size_t)row0 * 128))[tid];
    __syncthreads();
    float acc[8] = {0.f, 0.f, 0.f, 0.f, 0.f, 0.f, 0.f, 0.f};
    const float* __restrict__ Bc = B + tid;
#pragma unroll 4
    for (int k = 0; k < 128; ++k) {
        float wv = Bc[(size_t)k * 256];
#pragma unroll
        for (int r = 0; r < 8; ++r) acc[r] += As[r][k] * wv;
    }
#pragma unroll
    for (int r = 0; r < 8; ++r) C[(size_t)(row0 + r) * 256 + tid] = acc[r];
}

// C[M,64] = A[M,256] @ B[256,64]; 256 thr = 4 groups x 64 cols, 16 rows/block
__global__ void gemm_k256_n64(const float* __restrict__ A, const float* __restrict__ B,
                              float* __restrict__ C, int M) {
    __shared__ float As[16][256];
    const int row0 = blockIdx.x * 16;
    if (row0 >= M) return;
    const int tid = threadIdx.x;
    {
        const float4* src = (const float4*)(A + (size_t)row0 * 256);
        float4* dstl = (float4*)&As[0][0];
#pragma unroll
        for (int i = 0; i < 4; ++i) dstl[tid + i * 256] = src[tid + i * 256];
    }
    __syncthreads();
    const int col = tid & 63, g = tid >> 6;
    float acc[4] = {0.f, 0.f, 0.f, 0.f};
    const float* __restrict__ Bc = B + col;
#pragma unroll 4
    for (int k = 0; k < 256; ++k) {
        float wv = Bc[(size_t)k * 64];
#pragma unroll
        for (int r = 0; r < 4; ++r) acc[r] += As[g * 4 + r][k] * wv;
    }
#pragma unroll
    for (int r = 0; r < 4; ++r) C[(size_t)(row0 + g * 4 + r) * 64 + col] = acc[r];
}

// ---------------- attention dot products ----------------

__global__ void attn_h4(const float* __restrict__ h, const float* __restrict__ asrc,
                        const float* __restrict__ adst, float* __restrict__ os,
                        float* __restrict__ od, int N) {
    const int n = blockIdx.x;
    if (n >= N) return;
    const int t = threadIdx.x;            // 256
    float v = h[(size_t)n * 256 + t];
    float s = v * asrc[t];
    float d = v * adst[t];
#pragma unroll
    for (int m = 1; m < 64; m <<= 1) { s += __shfl_xor(s, m); d += __shfl_xor(d, m); }
    if ((t & 63) == 0) { os[n * 4 + (t >> 6)] = s; od[n * 4 + (t >> 6)] = d; }
}

__global__ void attn_h1(const float* __restrict__ h, const float* __restrict__ asrc,
                        const float* __restrict__ adst, float* __restrict__ os,
                        float* __restrict__ od, int N) {
    const int n = blockIdx.x * 4 + (threadIdx.x >> 6);
    if (n >= N) return;
    const int c = threadIdx.x & 63;
    float v = h[(size_t)n * 64 + c];
    float s = v * asrc[c];
    float d = v * adst[c];
#pragma unroll
    for (int m = 1; m < 64; m <<= 1) { s += __shfl_xor(s, m); d += __shfl_xor(d, m); }
    if (c == 0) { os[n] = s; od[n] = d; }
}

// ---------------- CSR build: histogram -> scan -> fill ----------------

__global__ void hist_k(const int* __restrict__ ei, int E, int* __restrict__ cnt) {
    int e = blockIdx.x * blockDim.x + threadIdx.x;
    if (e < E) atomicAdd(&cnt[ei[E + e]], 1);
}

// per-block exclusive scan; writes block sums
__global__ void scan1_k(const int* __restrict__ cnt, int* __restrict__ off,
                        int* __restrict__ bsum, int N) {
    __shared__ int tmp[256];
    const int i = blockIdx.x * 256 + threadIdx.x;
    int v = (i < N) ? cnt[i] : 0;
    tmp[threadIdx.x] = v;
    __syncthreads();
#pragma unroll
    for (int d = 1; d < 256; d <<= 1) {
        int t = (threadIdx.x >= d) ? tmp[threadIdx.x - d] : 0;
        __syncthreads();
        tmp[threadIdx.x] += t;
        __syncthreads();
    }
    if (i < N) off[i] = tmp[threadIdx.x] - v;   // exclusive within block
    if (threadIdx.x == 255) bsum[blockIdx.x] = tmp[255];
}

// single block exclusive scan of block sums (nb <= 256)
__global__ void scan2_k(int* __restrict__ bsum, int nb) {
    __shared__ int tmp[256];
    int v = (threadIdx.x < nb) ? bsum[threadIdx.x] : 0;
    tmp[threadIdx.x] = v;
    __syncthreads();
#pragma unroll
    for (int d = 1; d < 256; d <<= 1) {
        int t = (threadIdx.x >= d) ? tmp[threadIdx.x - d] : 0;
        __syncthreads();
        tmp[threadIdx.x] += t;
        __syncthreads();
    }
    if (threadIdx.x < nb) bsum[threadIdx.x] = tmp[threadIdx.x] - v;
}

__global__ void scan3_k(int* __restrict__ off, const int* __restrict__ bsum, int N) {
    int i = blockIdx.x * 256 + threadIdx.x;
    if (i < N) off[i] += bsum[blockIdx.x];
}

// scatter edge sources into CSR; off is mutated into "end" pointers
__global__ void fill_k(const int* __restrict__ ei, int E, int* __restrict__ off,
                       int* __restrict__ csr) {
    int e = blockIdx.x * blockDim.x + threadIdx.x;
    if (e >= E) return;
    int s = ei[e], d = ei[E + e];
    csr[atomicAdd(&off[d], 1)] = s;
}

// ---------------- pull aggregation with online softmax ----------------

// layer 1: H=4, C=64; one node per 256-thread block; fused bias + ReLU
__global__ __launch_bounds__(256) void agg1_k(
        const int* __restrict__ endp, const int* __restrict__ cnt,
        const int* __restrict__ csr, const float* __restrict__ h,
        const float* __restrict__ as, const float* __restrict__ ad,
        const float* __restrict__ bias, float* __restrict__ agg, int N) {
    const int n = blockIdx.x;
    if (n >= N) return;
    const int tid = threadIdx.x;
    const int hh = tid >> 6;
    const float adv = ad[n * 4 + hh];
    const int end = endp[n];
    const int start = end - cnt[n];
    float m = -__builtin_inff(), den = 0.f, acc = 0.f;
    int s_next = (start < end) ? csr[start] : 0;
    for (int i = start; i < end; ++i) {
        const int s = s_next;
        if (i + 1 < end) s_next = csr[i + 1];
        float e = as[s * 4 + hh] + adv;
        e = LRELU(e);
        if (e > m) {                       // wave-uniform branch (one head per wave)
            const float sc = __expf(m - e);
            den *= sc; acc *= sc; m = e;
        }
        const float p = __expf(e - m);
        den += p;
        acc += p * h[(size_t)s * 256 + tid];
    }
    {   // self-loop: src = dst = n
        float e = as[n * 4 + hh] + adv;
        e = LRELU(e);
        if (e > m) {
            const float sc = __expf(m - e);
            den *= sc; acc *= sc; m = e;
        }
        const float p = __expf(e - m);
        den += p;
        acc += p * h[(size_t)n * 256 + tid];
    }
    float v = acc / den + bias[tid];
    agg[(size_t)n * 256 + tid] = v > 0.f ? v : 0.f;
}

// layer 2: H=1, C=64; one wave per node (4/block); fused bias + L2 normalize
__global__ __launch_bounds__(256) void agg2_k(
        const int* __restrict__ endp, const int* __restrict__ cnt,
        const int* __restrict__ csr, const float* __restrict__ h,
        const float* __restrict__ as, const float* __restrict__ ad,
        const float* __restrict__ bias, float* __restrict__ out, int N) {
    const int n = blockIdx.x * 4 + (threadIdx.x >> 6);
    if (n >= N) return;
    const int c = threadIdx.x & 63;
    const float adv = ad[n];
    const int end = endp[n];
    const int start = end - cnt[n];
    float m = -__builtin_inff(), den = 0.f, acc = 0.f;
    int s_next = (start < end) ? csr[start] : 0;
    for (int i = start; i < end; ++i) {
        const int s = s_next;
        if (i + 1 < end) s_next = csr[i + 1];
        float e = as[s] + adv;
        e = LRELU(e);
        if (e > m) {
            const float sc = __expf(m - e);
            den *= sc; acc *= sc; m = e;
        }
        const float p = __expf(e - m);
        den += p;
        acc += p * h[(size_t)s * 64 + c];
    }
    {   // self-loop
        float e = as[n] + adv;
        e = LRELU(e);
        if (e > m) {
            const float sc = __expf(m - e);
            den *= sc; acc *= sc; m = e;
        }
        const float p = __expf(e - m);
        den += p;
        acc += p * h[(size_t)n * 64 + c];
    }
    float v = acc / den + bias[c];
    float ss = v * v;
#pragma unroll
    for (int mm = 1; mm < 64; mm <<= 1) ss += __shfl_xor(ss, mm);
    const float nrm = fmaxf(sqrtf(ss), 1e-12f);
    out[(size_t)n * 64 + c] = v / nrm;
}

// ---------------- launch ----------------

extern "C" void kernel_launch(void* const* d_in, const int* in_sizes, int n_in,
                              void* d_out, int out_size, void* d_ws, size_t ws_size,
                              hipStream_t stream) {
    const float* x   = (const float*)d_in[0];
    const int*   ei1 = (const int*)d_in[1];
    const int*   ei2 = (const int*)d_in[2];
    const float* W1  = (const float*)d_in[3];
    const float* as1 = (const float*)d_in[4];
    const float* ad1 = (const float*)d_in[5];
    const float* b1  = (const float*)d_in[6];
    const float* W2  = (const float*)d_in[7];
    const float* as2 = (const float*)d_in[8];
    const float* ad2 = (const float*)d_in[9];
    const float* b2  = (const float*)d_in[10];

    const int N  = in_sizes[0] / 128;
    const int E1 = in_sizes[1] / 2;
    const int E2 = in_sizes[2] / 2;
    const int Emax = E1 > E2 ? E1 : E2;

    // ws: only the two big node-feature buffers (102.4 MB)
    float* h1   = (float*)d_ws;                 // N*256 (layer-2 h reuses this region)
    float* agg1 = h1 + (size_t)N * 256;         // N*256 (final-out temp reuses this region)
    float* h2   = h1;
    float* otmp = agg1;

    // d_out doubles as scratch for CSR + attention logits until the final copy
    int*   csr  = (int*)d_out;                  // Emax
    int*   cnt  = csr + Emax;                   // N
    int*   off  = cnt + N;                      // N   (mutated into end-pointers by fill_k)
    int*   bsum = off + N;                      // 256
    float* s1   = (float*)(bsum + 256);         // N*4
    float* d1v  = s1 + (size_t)N * 4;           // N*4
    float* s2   = d1v + (size_t)N * 4;          // N
    float* d2v  = s2 + N;                       // N

    const int nb = (N + 255) / 256;             // scan blocks (196 <= 256)

    // ---- layer 1 ----
    gemm_k128_n256<<<(N + 7) / 8, 256, 0, stream>>>(x, W1, h1, N);
    attn_h4<<<N, 256, 0, stream>>>(h1, as1, ad1, s1, d1v, N);

    hipMemsetAsync(cnt, 0, (size_t)N * sizeof(int), stream);
    hist_k<<<(E1 + 255) / 256, 256, 0, stream>>>(ei1, E1, cnt);
    scan1_k<<<nb, 256, 0, stream>>>(cnt, off, bsum, N);
    scan2_k<<<1, 256, 0, stream>>>(bsum, nb);
    scan3_k<<<nb, 256, 0, stream>>>(off, bsum, N);
    fill_k<<<(E1 + 255) / 256, 256, 0, stream>>>(ei1, E1, off, csr);

    agg1_k<<<N, 256, 0, stream>>>(off, cnt, csr, h1, s1, d1v, b1, agg1, N);

    // ---- layer 2 ----
    gemm_k256_n64<<<(N + 15) / 16, 256, 0, stream>>>(agg1, W2, h2, N);
    attn_h1<<<(N + 3) / 4, 256, 0, stream>>>(h2, as2, ad2, s2, d2v, N);

    hipMemsetAsync(cnt, 0, (size_t)N * sizeof(int), stream);
    hist_k<<<(E2 + 255) / 256, 256, 0, stream>>>(ei2, E2, cnt);
    scan1_k<<<nb, 256, 0, stream>>>(cnt, off, bsum, N);
    scan2_k<<<1, 256, 0, stream>>>(bsum, nb);
    scan3_k<<<nb, 256, 0, stream>>>(off, bsum, N);
    fill_k<<<(E2 + 255) / 256, 256, 0, stream>>>(ei2, E2, off, csr);

    agg2_k<<<(N + 3) / 4, 256, 0, stream>>>(off, cnt, csr, h2, s2, d2v, b2, otmp, N);

    // ---- publish: overwrite d_out scratch with the result ----
    hipMemcpyAsync(d_out, otmp, (size_t)N * 64 * sizeof(float),
                   hipMemcpyDeviceToDevice, stream);
}